// Round 8
// baseline (594.801 us; speedup 1.0000x reference)
//
#include <hip/hip_runtime.h>
#include <math.h>

// CognitiveRouter: module routing (4) + grouped expert routing (16), combined
// hierarchical probs, top-4 + renorm.  T=32768, D=1536, fp32 in/out.
//
// R13 (R12 post-mortem: convoy theory falsified -- R5/R8/R9/R12, four
// different schedules, all ~57us = 201MB at ~3.5 TB/s realized. Fills in the
// same capture hit 6.8 TB/s with 32 waves/CU. Remaining theory: latency
// exposure at 2 waves/SIMD; occupancy never cleanly tested because the
// 20-wide weight-read hoist spills any VGPR cap <=128 (R6/R11).)
// Changes:
//  1. 256-thr blocks, __launch_bounds__(256,4): 4 blocks/CU, 16 waves/CU
//     (4/SIMD, 2x all prior variants). Grid 1024.
//  2. rows/lane=2 (acc=40) + e-loop GROUPED 5x4 so only 4 weight v4f are
//     live per group: ~100-110 live VGPR, fits the 128 cap WITHOUT spill
//     (the R6/R11 killer was 20 hoisted w-quads).
//  3. hs global->VGPR, R9-style j+=2 named-reg double-window prefetch
//     (verified structure). No hs LDS, no DMA, no waitcnt asm.
//  4. Weights in 6 LDS stages of 4 j-windows (20 KB/block; 4 blk x 20 KB =
//     80 KB/CU). R10-verified staging map scaled to 256 thr. 12 barriers.
//  5. Epilogue: R10/R11-verified q<2 form (rows rW+g, rW+g+4 per wave).
// Gate counters: WRITE_SIZE ~3MB (no spill) else abandon; router 58 -> ~40-46us
// if occupancy theory right, else ~3.5 TB/s is the pattern ceiling (roofline).

#define DD 1536
#define NM 4
#define NE 16
#define NW 20          // 16 expert rows + 4 module rows
#define NTHR 256
#define RPB 32         // 4 waves x 8 rows
#define NJ 24          // 64-col windows
#define SJ 4           // j-windows per weight stage
#define NSTAGE 6
#define WL_F (SJ * NW * 64)   // 5120 floats = 20480 B

typedef float v4f __attribute__((ext_vector_type(4)));

__device__ __forceinline__ void wstage(float* wl, const float* We, const float* Wm,
                                       int tid, int s)
{
#pragma unroll
    for (int it = 0; it < 5; it++) {
        const int off = tid * 4 + it * 1024;
        const int jw  = off / 1280;
        const int rem = off - jw * 1280;
        const int e   = rem >> 6;
        const int qc  = rem & 63;
        const int col = (s * SJ + jw) * 64 + qc;
        v4f w = (e < NE) ? *(const v4f*)(We + (size_t)e * DD + col)
                         : *(const v4f*)(Wm + (size_t)(e - NE) * DD + col);
        *(v4f*)&wl[off] = w;
    }
}

// one 64-col j-step for 2 rows; weights read in 5 groups of 4 (bounded lives)
__device__ __forceinline__ void jstep(const float* wl, int jw, int q,
                                      v4f ha, v4f hb, float* accA, float* accB)
{
    const float* wb = &wl[jw * 1280 + q * 4];
#pragma unroll
    for (int eg = 0; eg < 5; eg++) {
        v4f w0 = *(const v4f*)(wb + (eg * 4 + 0) * 64);
        v4f w1 = *(const v4f*)(wb + (eg * 4 + 1) * 64);
        v4f w2 = *(const v4f*)(wb + (eg * 4 + 2) * 64);
        v4f w3 = *(const v4f*)(wb + (eg * 4 + 3) * 64);
        float* aA = accA + eg * 4;
        float* aB = accB + eg * 4;
        aA[0] = fmaf(ha.x, w0.x, aA[0]); aA[0] = fmaf(ha.y, w0.y, aA[0]);
        aA[0] = fmaf(ha.z, w0.z, aA[0]); aA[0] = fmaf(ha.w, w0.w, aA[0]);
        aA[1] = fmaf(ha.x, w1.x, aA[1]); aA[1] = fmaf(ha.y, w1.y, aA[1]);
        aA[1] = fmaf(ha.z, w1.z, aA[1]); aA[1] = fmaf(ha.w, w1.w, aA[1]);
        aA[2] = fmaf(ha.x, w2.x, aA[2]); aA[2] = fmaf(ha.y, w2.y, aA[2]);
        aA[2] = fmaf(ha.z, w2.z, aA[2]); aA[2] = fmaf(ha.w, w2.w, aA[2]);
        aA[3] = fmaf(ha.x, w3.x, aA[3]); aA[3] = fmaf(ha.y, w3.y, aA[3]);
        aA[3] = fmaf(ha.z, w3.z, aA[3]); aA[3] = fmaf(ha.w, w3.w, aA[3]);
        aB[0] = fmaf(hb.x, w0.x, aB[0]); aB[0] = fmaf(hb.y, w0.y, aB[0]);
        aB[0] = fmaf(hb.z, w0.z, aB[0]); aB[0] = fmaf(hb.w, w0.w, aB[0]);
        aB[1] = fmaf(hb.x, w1.x, aB[1]); aB[1] = fmaf(hb.y, w1.y, aB[1]);
        aB[1] = fmaf(hb.z, w1.z, aB[1]); aB[1] = fmaf(hb.w, w1.w, aB[1]);
        aB[2] = fmaf(hb.x, w2.x, aB[2]); aB[2] = fmaf(hb.y, w2.y, aB[2]);
        aB[2] = fmaf(hb.z, w2.z, aB[2]); aB[2] = fmaf(hb.w, w2.w, aB[2]);
        aB[3] = fmaf(hb.x, w3.x, aB[3]); aB[3] = fmaf(hb.y, w3.y, aB[3]);
        aB[3] = fmaf(hb.z, w3.z, aB[3]); aB[3] = fmaf(hb.w, w3.w, aB[3]);
    }
}

__global__ __launch_bounds__(NTHR, 4)
void router_kernel(const float* __restrict__ hs,
                   const float* __restrict__ Wm,
                   const float* __restrict__ We,
                   float* __restrict__ out,
                   int T)
{
    __shared__ __align__(16) float wl[WL_F];   // 20 KB -> 4 blocks/CU
    const int tid  = threadIdx.x;
    const int wv   = tid >> 6;      // 0..3
    const int lane = tid & 63;
    const int q    = lane & 15;     // col slot within 64-col window
    const int g    = lane >> 4;     // row sub-group 0..3
    const int rW   = blockIdx.x * RPB + wv * 8;   // this wave's 8 rows

    const float* hsA = hs + (size_t)(rW + g) * DD + q * 4;   // row rW+g
    const float* hsB = hsA + (size_t)4 * DD;                 // row rW+g+4

    float accA[NW], accB[NW];
#pragma unroll
    for (int e = 0; e < NW; e++) { accA[e] = 0.f; accB[e] = 0.f; }

    // prefetch windows 0,1 (in flight under stage-0 weight staging)
    v4f a0 = *(const v4f*)(hsA);
    v4f b0 = *(const v4f*)(hsB);
    v4f a1 = *(const v4f*)(hsA + 64);
    v4f b1 = *(const v4f*)(hsB + 64);

#pragma unroll 1
    for (int s = 0; s < NSTAGE; s++) {
        if (s) __syncthreads();            // all waves done with prev stage
        wstage(wl, We, Wm, tid, s);
        __syncthreads();

        const int j0 = s * SJ;
        // pair 0: compute jw 0,1; prefetch windows j0+2, j0+3 (always in range)
        v4f a2 = *(const v4f*)(hsA + (size_t)(j0 + 2) * 64);
        v4f b2 = *(const v4f*)(hsB + (size_t)(j0 + 2) * 64);
        v4f a3 = *(const v4f*)(hsA + (size_t)(j0 + 3) * 64);
        v4f b3 = *(const v4f*)(hsB + (size_t)(j0 + 3) * 64);
        jstep(wl, 0, q, a0, b0, accA, accB);
        jstep(wl, 1, q, a1, b1, accA, accB);
        // pair 1: compute jw 2,3; prefetch next stage's windows j0+4, j0+5
        if (s + 1 < NSTAGE) {
            a0 = *(const v4f*)(hsA + (size_t)(j0 + 4) * 64);
            b0 = *(const v4f*)(hsB + (size_t)(j0 + 4) * 64);
            a1 = *(const v4f*)(hsA + (size_t)(j0 + 5) * 64);
            b1 = *(const v4f*)(hsB + (size_t)(j0 + 5) * 64);
        }
        jstep(wl, 2, q, a2, b2, accA, accB);
        jstep(wl, 3, q, a3, b3, accA, accB);
    }

    // ---- in-register split-col reduction over the 16 q-lanes ----
#pragma unroll
    for (int e = 0; e < NW; e++) {
        accA[e] += __shfl_xor(accA[e], 1); accA[e] += __shfl_xor(accA[e], 2);
        accA[e] += __shfl_xor(accA[e], 4); accA[e] += __shfl_xor(accA[e], 8);
        accB[e] += __shfl_xor(accB[e], 1); accB[e] += __shfl_xor(accB[e], 2);
        accB[e] += __shfl_xor(accB[e], 4); accB[e] += __shfl_xor(accB[e], 8);
    }

    // ---- epilogue (R10/R11-verified): q==0 -> row rW+g, q==1 -> rW+g+4 ----
    if (q < 2) {
        float logit[NW];
#pragma unroll
        for (int e = 0; e < NW; e++) logit[e] = q ? accB[e] : accA[e];
        const int row = rW + g + (q ? 4 : 0);

        // module softmax over logit[16..19]
        float mmax = logit[16];
#pragma unroll
        for (int m = 1; m < NM; m++) mmax = fmaxf(mmax, logit[16 + m]);
        float mexp[NM], msum = 0.f;
#pragma unroll
        for (int m = 0; m < NM; m++) { mexp[m] = expf(logit[16 + m] - mmax); msum += mexp[m]; }

        // per-module expert softmax, combined probs
        float comb[NE];
#pragma unroll
        for (int m = 0; m < NM; m++) {
            float mprob = mexp[m] / msum;
            float emax = logit[m * 4];
#pragma unroll
            for (int jj = 1; jj < 4; jj++) emax = fmaxf(emax, logit[m * 4 + jj]);
            float ee[4], esum = 0.f;
#pragma unroll
            for (int jj = 0; jj < 4; jj++) { ee[jj] = expf(logit[m * 4 + jj] - emax); esum += ee[jj]; }
            float scale = mprob / esum;
#pragma unroll
            for (int jj = 0; jj < 4; jj++) comb[m * 4 + jj] = ee[jj] * scale;
        }

        float4* cw = (float4*)(out + (size_t)row * 16);
        cw[0] = make_float4(comb[0],  comb[1],  comb[2],  comb[3]);
        cw[1] = make_float4(comb[4],  comb[5],  comb[6],  comb[7]);
        cw[2] = make_float4(comb[8],  comb[9],  comb[10], comb[11]);
        cw[3] = make_float4(comb[12], comb[13], comb[14], comb[15]);

        // top-4, descending, strict > so lowest index wins ties (lax.top_k)
        float tv[4]; int ti[4];
        unsigned mask = 0;
#pragma unroll
        for (int k = 0; k < 4; k++) {
            float best = -1.f; int bi = 0;
#pragma unroll
            for (int i = 0; i < NE; i++) {
                bool avail = !((mask >> i) & 1u);
                if (avail && comb[i] > best) { best = comb[i]; bi = i; }
            }
            tv[k] = best; ti[k] = bi; mask |= 1u << bi;
        }
        float s = tv[0] + tv[1] + tv[2] + tv[3] + 1e-8f;

        const size_t wOff = (size_t)T * 16;          // top_k_weights region
        const size_t iOff = (size_t)T * 20;          // top_k_indices region
        float4* ww = (float4*)(out + wOff + (size_t)row * 4);
        *ww = make_float4(tv[0] / s, tv[1] / s, tv[2] / s, tv[3] / s);
        float4* iw = (float4*)(out + iOff + (size_t)row * 4);
        *iw = make_float4((float)ti[0], (float)ti[1], (float)ti[2], (float)ti[3]);
    }
}

extern "C" void kernel_launch(void* const* d_in, const int* in_sizes, int n_in,
                              void* d_out, int out_size, void* d_ws, size_t ws_size,
                              hipStream_t stream)
{
    const float* hs = (const float*)d_in[0];   // (T, 1536)
    const float* Wm = (const float*)d_in[1];   // (4, 1536)
    const float* We = (const float*)d_in[2];   // (16, 1536)
    float* out = (float*)d_out;
    const int T = in_sizes[0] / DD;            // 32768
    router_kernel<<<T / RPB, NTHR, 0, stream>>>(hs, Wm, We, out, T);
}

// Round 9
// 306.699 us; speedup vs baseline: 1.9394x; 1.9394x over previous
//
#include <hip/hip_runtime.h>
#include <math.h>

// CognitiveRouter: module routing (4) + grouped expert routing (16), combined
// hierarchical probs, top-4 + renorm.  T=32768, D=1536, fp32 in/out.
//
// R14 (R13 post-mortem: VGPR_Count=64 != the 128 my (256,4) model predicted;
// WRITE 869MB spill, 400us. Third straight round lost to launch_bounds arg2.
// Empirical rule: NEVER pass arg2; uncapped RA allocates to pressure and a
// ~110-VGPR kernel lands in the <=128 bucket = 4 waves/SIMD spill-free.)
// R14 = R13 with ONE change: __launch_bounds__(256), no min-waves arg.
//   Expected: VGPR 96-128, no spill, 4 blocks/CU (LDS 80KB), 16 waves/CU --
//   the clean occupancy A/B vs the ~57us 8-wave family (R5/R8/R9/R12).
// Pre-committed read: ~40-46us => occupancy was the limit; ~57us spill-free
//   => pattern/read-path ceiling (next: one-stream-per-wave rows or roofline).
// Keep (R13, verified): 2 rows/lane (acc=40), e-loop grouped 5x4 (bounded
// weight lives), hs global->VGPR named-reg prefetch, weights 6 LDS stages
// of 4 j-windows (20KB), __shfl_xor reduce, R10/R11 epilogue.

#define DD 1536
#define NM 4
#define NE 16
#define NW 20          // 16 expert rows + 4 module rows
#define NTHR 256
#define RPB 32         // 4 waves x 8 rows
#define NJ 24          // 64-col windows
#define SJ 4           // j-windows per weight stage
#define NSTAGE 6
#define WL_F (SJ * NW * 64)   // 5120 floats = 20480 B

typedef float v4f __attribute__((ext_vector_type(4)));

__device__ __forceinline__ void wstage(float* wl, const float* We, const float* Wm,
                                       int tid, int s)
{
#pragma unroll
    for (int it = 0; it < 5; it++) {
        const int off = tid * 4 + it * 1024;
        const int jw  = off / 1280;
        const int rem = off - jw * 1280;
        const int e   = rem >> 6;
        const int qc  = rem & 63;
        const int col = (s * SJ + jw) * 64 + qc;
        v4f w = (e < NE) ? *(const v4f*)(We + (size_t)e * DD + col)
                         : *(const v4f*)(Wm + (size_t)(e - NE) * DD + col);
        *(v4f*)&wl[off] = w;
    }
}

// one 64-col j-step for 2 rows; weights read in 5 groups of 4 (bounded lives)
__device__ __forceinline__ void jstep(const float* wl, int jw, int q,
                                      v4f ha, v4f hb, float* accA, float* accB)
{
    const float* wb = &wl[jw * 1280 + q * 4];
#pragma unroll
    for (int eg = 0; eg < 5; eg++) {
        v4f w0 = *(const v4f*)(wb + (eg * 4 + 0) * 64);
        v4f w1 = *(const v4f*)(wb + (eg * 4 + 1) * 64);
        v4f w2 = *(const v4f*)(wb + (eg * 4 + 2) * 64);
        v4f w3 = *(const v4f*)(wb + (eg * 4 + 3) * 64);
        float* aA = accA + eg * 4;
        float* aB = accB + eg * 4;
        aA[0] = fmaf(ha.x, w0.x, aA[0]); aA[0] = fmaf(ha.y, w0.y, aA[0]);
        aA[0] = fmaf(ha.z, w0.z, aA[0]); aA[0] = fmaf(ha.w, w0.w, aA[0]);
        aA[1] = fmaf(ha.x, w1.x, aA[1]); aA[1] = fmaf(ha.y, w1.y, aA[1]);
        aA[1] = fmaf(ha.z, w1.z, aA[1]); aA[1] = fmaf(ha.w, w1.w, aA[1]);
        aA[2] = fmaf(ha.x, w2.x, aA[2]); aA[2] = fmaf(ha.y, w2.y, aA[2]);
        aA[2] = fmaf(ha.z, w2.z, aA[2]); aA[2] = fmaf(ha.w, w2.w, aA[2]);
        aA[3] = fmaf(ha.x, w3.x, aA[3]); aA[3] = fmaf(ha.y, w3.y, aA[3]);
        aA[3] = fmaf(ha.w, w3.w, aA[3]); aA[3] = fmaf(ha.z, w3.z, aA[3]);
        aB[0] = fmaf(hb.x, w0.x, aB[0]); aB[0] = fmaf(hb.y, w0.y, aB[0]);
        aB[0] = fmaf(hb.z, w0.z, aB[0]); aB[0] = fmaf(hb.w, w0.w, aB[0]);
        aB[1] = fmaf(hb.x, w1.x, aB[1]); aB[1] = fmaf(hb.y, w1.y, aB[1]);
        aB[1] = fmaf(hb.z, w1.z, aB[1]); aB[1] = fmaf(hb.w, w1.w, aB[1]);
        aB[2] = fmaf(hb.x, w2.x, aB[2]); aB[2] = fmaf(hb.y, w2.y, aB[2]);
        aB[2] = fmaf(hb.z, w2.z, aB[2]); aB[2] = fmaf(hb.w, w2.w, aB[2]);
        aB[3] = fmaf(hb.x, w3.x, aB[3]); aB[3] = fmaf(hb.y, w3.y, aB[3]);
        aB[3] = fmaf(hb.z, w3.z, aB[3]); aB[3] = fmaf(hb.w, w3.w, aB[3]);
    }
}

__global__ __launch_bounds__(NTHR)
void router_kernel(const float* __restrict__ hs,
                   const float* __restrict__ Wm,
                   const float* __restrict__ We,
                   float* __restrict__ out,
                   int T)
{
    __shared__ __align__(16) float wl[WL_F];   // 20 KB
    const int tid  = threadIdx.x;
    const int wv   = tid >> 6;      // 0..3
    const int lane = tid & 63;
    const int q    = lane & 15;     // col slot within 64-col window
    const int g    = lane >> 4;     // row sub-group 0..3
    const int rW   = blockIdx.x * RPB + wv * 8;   // this wave's 8 rows

    const float* hsA = hs + (size_t)(rW + g) * DD + q * 4;   // row rW+g
    const float* hsB = hsA + (size_t)4 * DD;                 // row rW+g+4

    float accA[NW], accB[NW];
#pragma unroll
    for (int e = 0; e < NW; e++) { accA[e] = 0.f; accB[e] = 0.f; }

    // prefetch windows 0,1 (in flight under stage-0 weight staging)
    v4f a0 = *(const v4f*)(hsA);
    v4f b0 = *(const v4f*)(hsB);
    v4f a1 = *(const v4f*)(hsA + 64);
    v4f b1 = *(const v4f*)(hsB + 64);

#pragma unroll 1
    for (int s = 0; s < NSTAGE; s++) {
        if (s) __syncthreads();            // all waves done with prev stage
        wstage(wl, We, Wm, tid, s);
        __syncthreads();

        const int j0 = s * SJ;
        // pair 0: compute jw 0,1; prefetch windows j0+2, j0+3 (always in range)
        v4f a2 = *(const v4f*)(hsA + (size_t)(j0 + 2) * 64);
        v4f b2 = *(const v4f*)(hsB + (size_t)(j0 + 2) * 64);
        v4f a3 = *(const v4f*)(hsA + (size_t)(j0 + 3) * 64);
        v4f b3 = *(const v4f*)(hsB + (size_t)(j0 + 3) * 64);
        jstep(wl, 0, q, a0, b0, accA, accB);
        jstep(wl, 1, q, a1, b1, accA, accB);
        // pair 1: compute jw 2,3; prefetch next stage's windows j0+4, j0+5
        if (s + 1 < NSTAGE) {
            a0 = *(const v4f*)(hsA + (size_t)(j0 + 4) * 64);
            b0 = *(const v4f*)(hsB + (size_t)(j0 + 4) * 64);
            a1 = *(const v4f*)(hsA + (size_t)(j0 + 5) * 64);
            b1 = *(const v4f*)(hsB + (size_t)(j0 + 5) * 64);
        }
        jstep(wl, 2, q, a2, b2, accA, accB);
        jstep(wl, 3, q, a3, b3, accA, accB);
    }

    // ---- in-register split-col reduction over the 16 q-lanes ----
#pragma unroll
    for (int e = 0; e < NW; e++) {
        accA[e] += __shfl_xor(accA[e], 1); accA[e] += __shfl_xor(accA[e], 2);
        accA[e] += __shfl_xor(accA[e], 4); accA[e] += __shfl_xor(accA[e], 8);
        accB[e] += __shfl_xor(accB[e], 1); accB[e] += __shfl_xor(accB[e], 2);
        accB[e] += __shfl_xor(accB[e], 4); accB[e] += __shfl_xor(accB[e], 8);
    }

    // ---- epilogue (R10/R11-verified): q==0 -> row rW+g, q==1 -> rW+g+4 ----
    if (q < 2) {
        float logit[NW];
#pragma unroll
        for (int e = 0; e < NW; e++) logit[e] = q ? accB[e] : accA[e];
        const int row = rW + g + (q ? 4 : 0);

        // module softmax over logit[16..19]
        float mmax = logit[16];
#pragma unroll
        for (int m = 1; m < NM; m++) mmax = fmaxf(mmax, logit[16 + m]);
        float mexp[NM], msum = 0.f;
#pragma unroll
        for (int m = 0; m < NM; m++) { mexp[m] = expf(logit[16 + m] - mmax); msum += mexp[m]; }

        // per-module expert softmax, combined probs
        float comb[NE];
#pragma unroll
        for (int m = 0; m < NM; m++) {
            float mprob = mexp[m] / msum;
            float emax = logit[m * 4];
#pragma unroll
            for (int jj = 1; jj < 4; jj++) emax = fmaxf(emax, logit[m * 4 + jj]);
            float ee[4], esum = 0.f;
#pragma unroll
            for (int jj = 0; jj < 4; jj++) { ee[jj] = expf(logit[m * 4 + jj] - emax); esum += ee[jj]; }
            float scale = mprob / esum;
#pragma unroll
            for (int jj = 0; jj < 4; jj++) comb[m * 4 + jj] = ee[jj] * scale;
        }

        float4* cw = (float4*)(out + (size_t)row * 16);
        cw[0] = make_float4(comb[0],  comb[1],  comb[2],  comb[3]);
        cw[1] = make_float4(comb[4],  comb[5],  comb[6],  comb[7]);
        cw[2] = make_float4(comb[8],  comb[9],  comb[10], comb[11]);
        cw[3] = make_float4(comb[12], comb[13], comb[14], comb[15]);

        // top-4, descending, strict > so lowest index wins ties (lax.top_k)
        float tv[4]; int ti[4];
        unsigned mask = 0;
#pragma unroll
        for (int k = 0; k < 4; k++) {
            float best = -1.f; int bi = 0;
#pragma unroll
            for (int i = 0; i < NE; i++) {
                bool avail = !((mask >> i) & 1u);
                if (avail && comb[i] > best) { best = comb[i]; bi = i; }
            }
            tv[k] = best; ti[k] = bi; mask |= 1u << bi;
        }
        float s = tv[0] + tv[1] + tv[2] + tv[3] + 1e-8f;

        const size_t wOff = (size_t)T * 16;          // top_k_weights region
        const size_t iOff = (size_t)T * 20;          // top_k_indices region
        float4* ww = (float4*)(out + wOff + (size_t)row * 4);
        *ww = make_float4(tv[0] / s, tv[1] / s, tv[2] / s, tv[3] / s);
        float4* iw = (float4*)(out + iOff + (size_t)row * 4);
        *iw = make_float4((float)ti[0], (float)ti[1], (float)ti[2], (float)ti[3]);
    }
}

extern "C" void kernel_launch(void* const* d_in, const int* in_sizes, int n_in,
                              void* d_out, int out_size, void* d_ws, size_t ws_size,
                              hipStream_t stream)
{
    const float* hs = (const float*)d_in[0];   // (T, 1536)
    const float* Wm = (const float*)d_in[1];   // (4, 1536)
    const float* We = (const float*)d_in[2];   // (16, 1536)
    float* out = (float*)d_out;
    const int T = in_sizes[0] / DD;            // 32768
    router_kernel<<<T / RPB, NTHR, 0, stream>>>(hs, Wm, We, out, T);
}

// Round 11
// 294.080 us; speedup vs baseline: 2.0226x; 1.0429x over previous
//
#include <hip/hip_runtime.h>
#include <math.h>

// CognitiveRouter: module routing (4) + grouped expert routing (16), combined
// hierarchical probs, top-4 + renorm.  T=32768, D=1536, fp32 in/out.
//
// R16 = R15 resubmitted verbatim (round 10 was an infra failure: "MI355X
// container failed twice" -- no counters, the occupancy A/B never ran).
//
// R15 rationale (R14 post-mortem: no spill but 140us -- the 6-stage/
// 12-barrier structure exposed per-stage weight-restage latency; occupancy
// test confounded AGAIN. Also: FETCH=100MB < 201MB hs => input partially
// L3-resident; and VALUBusy*dur ~ 39us >> 12.8us pure FMA in every variant.)
// R15 = the CLEAN occupancy A/B vs the ~57us 8-wave family (R8/R9/R12):
//  1. R8's schedule: stage weights, then UNINTERRUPTED j-run; register
//     prefetch; shfl reduce; verified epilogue. Only ONE restage pair
//     (weights in 2 stages of 12 j-windows, 61.4KB LDS).
//  2. Budgeted for natural VGPR <= 128 (no launch_bounds arg2 -- R10/11/13
//     all died to it): 2 rows/lane (acc 40), depth-2 window prefetch
//     (6 h-bufs), grouped 5x4 weight reads. ~100-110 live.
//     => 4 waves/SIMD, 2 blocks/CU (2x61.4KB LDS), 16 waves/CU: 2x the
//     57-family's occupancy with the SAME inner structure.
// Gate: VGPR_Count <= 128 (129-170 voids the test). Pre-committed read:
//  router ~40-46us => occupancy was the limit; ~57us at 16 waves/CU =>
//  plateau is intrinsic (VALU/addressing overhead), declare roofline next.

#define DD 1536
#define NM 4
#define NE 16
#define NW 20          // 16 expert rows + 4 module rows
#define NTHR 512
#define NWAVE 8
#define RPB 64         // 8 waves x 8 rows
#define NJ 24          // 64-col windows
#define SJ 12          // j-windows per weight stage
#define NSTAGE 2
#define WL_F (SJ * NW * 64)   // 15360 floats = 61440 B -> 2 blocks/CU

typedef float v4f __attribute__((ext_vector_type(4)));

__device__ __forceinline__ void wstage(float* wl, const float* We, const float* Wm,
                                       int tid, int s)
{
    // 15360 floats = 512 thr x 7.5 v4f: 8 iters, last half-guarded.
#pragma unroll
    for (int it = 0; it < 8; it++) {
        const int off = tid * 4 + it * 2048;
        if (off < WL_F) {
            const int jw  = off / 1280;
            const int rem = off - jw * 1280;
            const int e   = rem >> 6;
            const int qc  = rem & 63;
            const int col = (s * SJ + jw) * 64 + qc;
            v4f w = (e < NE) ? *(const v4f*)(We + (size_t)e * DD + col)
                             : *(const v4f*)(Wm + (size_t)(e - NE) * DD + col);
            *(v4f*)&wl[off] = w;
        }
    }
}

// one 64-col j-step for 2 rows; weights read in 5 groups of 4 (bounded lives)
__device__ __forceinline__ void jstep(const float* wl, int jw, int q,
                                      v4f ha, v4f hb, float* accA, float* accB)
{
    const float* wb = &wl[jw * 1280 + q * 4];
#pragma unroll
    for (int eg = 0; eg < 5; eg++) {
        v4f w0 = *(const v4f*)(wb + (eg * 4 + 0) * 64);
        v4f w1 = *(const v4f*)(wb + (eg * 4 + 1) * 64);
        v4f w2 = *(const v4f*)(wb + (eg * 4 + 2) * 64);
        v4f w3 = *(const v4f*)(wb + (eg * 4 + 3) * 64);
        float* aA = accA + eg * 4;
        float* aB = accB + eg * 4;
        aA[0] = fmaf(ha.x, w0.x, aA[0]); aA[0] = fmaf(ha.y, w0.y, aA[0]);
        aA[0] = fmaf(ha.z, w0.z, aA[0]); aA[0] = fmaf(ha.w, w0.w, aA[0]);
        aA[1] = fmaf(ha.x, w1.x, aA[1]); aA[1] = fmaf(ha.y, w1.y, aA[1]);
        aA[1] = fmaf(ha.z, w1.z, aA[1]); aA[1] = fmaf(ha.w, w1.w, aA[1]);
        aA[2] = fmaf(ha.x, w2.x, aA[2]); aA[2] = fmaf(ha.y, w2.y, aA[2]);
        aA[2] = fmaf(ha.z, w2.z, aA[2]); aA[2] = fmaf(ha.w, w2.w, aA[2]);
        aA[3] = fmaf(ha.x, w3.x, aA[3]); aA[3] = fmaf(ha.y, w3.y, aA[3]);
        aA[3] = fmaf(ha.z, w3.z, aA[3]); aA[3] = fmaf(ha.w, w3.w, aA[3]);
        aB[0] = fmaf(hb.x, w0.x, aB[0]); aB[0] = fmaf(hb.y, w0.y, aB[0]);
        aB[0] = fmaf(hb.z, w0.z, aB[0]); aB[0] = fmaf(hb.w, w0.w, aB[0]);
        aB[1] = fmaf(hb.x, w1.x, aB[1]); aB[1] = fmaf(hb.y, w1.y, aB[1]);
        aB[1] = fmaf(hb.z, w1.z, aB[1]); aB[1] = fmaf(hb.w, w1.w, aB[1]);
        aB[2] = fmaf(hb.x, w2.x, aB[2]); aB[2] = fmaf(hb.y, w2.y, aB[2]);
        aB[2] = fmaf(hb.z, w2.z, aB[2]); aB[2] = fmaf(hb.w, w2.w, aB[2]);
        aB[3] = fmaf(hb.x, w3.x, aB[3]); aB[3] = fmaf(hb.y, w3.y, aB[3]);
        aB[3] = fmaf(hb.z, w3.z, aB[3]); aB[3] = fmaf(hb.w, w3.w, aB[3]);
    }
}

__global__ __launch_bounds__(NTHR)
void router_kernel(const float* __restrict__ hs,
                   const float* __restrict__ Wm,
                   const float* __restrict__ We,
                   float* __restrict__ out,
                   int T)
{
    __shared__ __align__(16) float wl[WL_F];   // 61.4 KB -> 2 blocks/CU
    const int tid  = threadIdx.x;
    const int wv   = tid >> 6;
    const int lane = tid & 63;
    const int q    = lane & 15;     // col slot within 64-col window
    const int g    = lane >> 4;     // row sub-group 0..3
    const int rW   = blockIdx.x * RPB + wv * 8;   // this wave's 8 rows

    const float* hsA = hs + (size_t)(rW + g) * DD + q * 4;   // row rW+g
    const float* hsB = hsA + (size_t)4 * DD;                 // row rW+g+4

    float accA[NW], accB[NW];
#pragma unroll
    for (int e = 0; e < NW; e++) { accA[e] = 0.f; accB[e] = 0.f; }

    // depth-2 prefetch: windows 0,1 in flight under stage-0 staging
    v4f a0 = *(const v4f*)(hsA);
    v4f b0 = *(const v4f*)(hsB);
    v4f a1 = *(const v4f*)(hsA + 64);
    v4f b1 = *(const v4f*)(hsB + 64);

    wstage(wl, We, Wm, tid, 0);
    __syncthreads();

#pragma unroll 1
    for (int s = 0; s < NSTAGE; s++) {
        if (s) {
            __syncthreads();               // all waves done with stage-0 wl
            wstage(wl, We, Wm, tid, s);
            __syncthreads();
        }
#pragma unroll 1
        for (int jj = 0; jj < SJ; jj++) {
            const int j = s * SJ + jj;
            v4f a2, b2;
            if (j + 2 < NJ) {
                a2 = *(const v4f*)(hsA + (size_t)(j + 2) * 64);
                b2 = *(const v4f*)(hsB + (size_t)(j + 2) * 64);
            }
            jstep(wl, jj, q, a0, b0, accA, accB);
            a0 = a1; b0 = b1; a1 = a2; b1 = b2;
        }
    }

    // ---- in-register split-col reduction over the 16 q-lanes ----
#pragma unroll
    for (int e = 0; e < NW; e++) {
        accA[e] += __shfl_xor(accA[e], 1); accA[e] += __shfl_xor(accA[e], 2);
        accA[e] += __shfl_xor(accA[e], 4); accA[e] += __shfl_xor(accA[e], 8);
        accB[e] += __shfl_xor(accB[e], 1); accB[e] += __shfl_xor(accB[e], 2);
        accB[e] += __shfl_xor(accB[e], 4); accB[e] += __shfl_xor(accB[e], 8);
    }

    // ---- epilogue (verified): q==0 -> row rW+g, q==1 -> rW+g+4 ----
    if (q < 2) {
        float logit[NW];
#pragma unroll
        for (int e = 0; e < NW; e++) logit[e] = q ? accB[e] : accA[e];
        const int row = rW + g + (q ? 4 : 0);

        // module softmax over logit[16..19]
        float mmax = logit[16];
#pragma unroll
        for (int m = 1; m < NM; m++) mmax = fmaxf(mmax, logit[16 + m]);
        float mexp[NM], msum = 0.f;
#pragma unroll
        for (int m = 0; m < NM; m++) { mexp[m] = expf(logit[16 + m] - mmax); msum += mexp[m]; }

        // per-module expert softmax, combined probs
        float comb[NE];
#pragma unroll
        for (int m = 0; m < NM; m++) {
            float mprob = mexp[m] / msum;
            float emax = logit[m * 4];
#pragma unroll
            for (int jj = 1; jj < 4; jj++) emax = fmaxf(emax, logit[m * 4 + jj]);
            float ee[4], esum = 0.f;
#pragma unroll
            for (int jj = 0; jj < 4; jj++) { ee[jj] = expf(logit[m * 4 + jj] - emax); esum += ee[jj]; }
            float scale = mprob / esum;
#pragma unroll
            for (int jj = 0; jj < 4; jj++) comb[m * 4 + jj] = ee[jj] * scale;
        }

        float4* cw = (float4*)(out + (size_t)row * 16);
        cw[0] = make_float4(comb[0],  comb[1],  comb[2],  comb[3]);
        cw[1] = make_float4(comb[4],  comb[5],  comb[6],  comb[7]);
        cw[2] = make_float4(comb[8],  comb[9],  comb[10], comb[11]);
        cw[3] = make_float4(comb[12], comb[13], comb[14], comb[15]);

        // top-4, descending, strict > so lowest index wins ties (lax.top_k)
        float tv[4]; int ti[4];
        unsigned mask = 0;
#pragma unroll
        for (int k = 0; k < 4; k++) {
            float best = -1.f; int bi = 0;
#pragma unroll
            for (int i = 0; i < NE; i++) {
                bool avail = !((mask >> i) & 1u);
                if (avail && comb[i] > best) { best = comb[i]; bi = i; }
            }
            tv[k] = best; ti[k] = bi; mask |= 1u << bi;
        }
        float s = tv[0] + tv[1] + tv[2] + tv[3] + 1e-8f;

        const size_t wOff = (size_t)T * 16;          // top_k_weights region
        const size_t iOff = (size_t)T * 20;          // top_k_indices region
        float4* ww = (float4*)(out + wOff + (size_t)row * 4);
        *ww = make_float4(tv[0] / s, tv[1] / s, tv[2] / s, tv[3] / s);
        float4* iw = (float4*)(out + iOff + (size_t)row * 4);
        *iw = make_float4((float)ti[0], (float)ti[1], (float)ti[2], (float)ti[3]);
    }
}

extern "C" void kernel_launch(void* const* d_in, const int* in_sizes, int n_in,
                              void* d_out, int out_size, void* d_ws, size_t ws_size,
                              hipStream_t stream)
{
    const float* hs = (const float*)d_in[0];   // (T, 1536)
    const float* Wm = (const float*)d_in[1];   // (4, 1536)
    const float* We = (const float*)d_in[2];   // (16, 1536)
    float* out = (float*)d_out;
    const int T = in_sizes[0] / DD;            // 32768
    router_kernel<<<T / RPB, NTHR, 0, stream>>>(hs, Wm, We, out, T);
}